// Round 11
// baseline (396.753 us; speedup 1.0000x reference)
//
#include <hip/hip_runtime.h>
#include <hip/hip_bf16.h>

#define NN 50000
#define EE 800000
#define GG 16
#define QD 768
#define NBUCK 196      // ceil(50000/256) dst-buckets of 256 nodes
#define EPB 4000       // edges per block in bin_edges (200 blocks)

#define AGG_GRID 2048            // long-lived blocks: 8/CU
#define AGG_STRIDE (AGG_GRID * 4)

typedef __bf16 bf16x8 __attribute__((ext_vector_type(8)));
typedef float f32x4 __attribute__((ext_vector_type(4)));
typedef int v4i __attribute__((ext_vector_type(4)));

// raw buffer loads (HW bounds check: OOB returns 0 — validated rounds 6/7).
extern "C" __device__ int __llvm_amdgcn_raw_buffer_load_i32(v4i rsrc, int voffset,
                                                            int soffset, int aux)
    __asm("llvm.amdgcn.raw.buffer.load.i32");
extern "C" __device__ v4i __llvm_amdgcn_raw_buffer_load_v4i32(v4i rsrc, int voffset,
                                                              int soffset, int aux)
    __asm("llvm.amdgcn.raw.buffer.load.v4i32");

static __device__ __forceinline__ float bflo(unsigned u) {
    union { unsigned v; float f; } c; c.v = u << 16; return c.f;
}
static __device__ __forceinline__ float bfhi(unsigned u) {
    union { unsigned v; float f; } c; c.v = u & 0xffff0000u; return c.f;
}

// ---------- fused prep + bucket_hist, range-dispatched ----------
// W5T[o][k], k in [0,640): k<128 -> root[k][o]; else r=(k-128)>>7 -> W[r][(k-128)&127][o]

#define PB_CVT 6250                 // NN*128/4 / 256
#define PB_W0  (PB_CVT + 160)       // 64*640/256
#define PB_W1  (PB_W0 + 320)       // 128*640/256
#define PB_W2  (PB_W1 + 320)
#define PB_W3  (PB_W2 + 160)
#define PB_Q   (PB_W3 + 16)         // 16 graphs, one block each
#define PB_Z   (PB_Q + 1)           // zero extended rows NN of xb0/xb1
#define PB_HIST (PB_Z + 256)        // 256 histogram blocks (bcnt pre-zeroed by memset)

__global__ __launch_bounds__(256) void prep_hist(
        const float* __restrict__ x, __hip_bfloat16* __restrict__ xb0e,
        __hip_bfloat16* __restrict__ xb1e,
        const float* __restrict__ qe, const float* __restrict__ qn_W,
        const float* __restrict__ qn_b, float* __restrict__ q,
        const float* __restrict__ W0, const float* __restrict__ root0, __hip_bfloat16* __restrict__ W5T0,
        const float* __restrict__ W1, const float* __restrict__ root1, __hip_bfloat16* __restrict__ W5T1,
        const float* __restrict__ W2, const float* __restrict__ root2, __hip_bfloat16* __restrict__ W5T2,
        const float* __restrict__ W3, const float* __restrict__ root3, __hip_bfloat16* __restrict__ W5T3,
        const int* __restrict__ edst, int* __restrict__ bcnt) {
    __shared__ float red[256];
    int blk = blockIdx.x, tid = threadIdx.x;
    if (blk < PB_CVT) {
        int i = blk * 256 + tid;              // float4 index
        float4 v = ((const float4*)x)[i];
        union { ushort4 u; __hip_bfloat16 h[4]; } o;
        o.h[0] = __float2bfloat16(v.x); o.h[1] = __float2bfloat16(v.y);
        o.h[2] = __float2bfloat16(v.z); o.h[3] = __float2bfloat16(v.w);
        ((ushort4*)xb0e)[i] = o.u;
    } else if (blk < PB_W3) {
        const float* W; const float* root; __hip_bfloat16* WT; int O, base;
        if (blk < PB_W0)      { W = W0; root = root0; WT = W5T0; O = 64;  base = PB_CVT; }
        else if (blk < PB_W1) { W = W1; root = root1; WT = W5T1; O = 128; base = PB_W0; }
        else if (blk < PB_W2) { W = W2; root = root2; WT = W5T2; O = 128; base = PB_W1; }
        else                  { W = W3; root = root3; WT = W5T3; O = 64;  base = PB_W2; }
        int idx = (blk - base) * 256 + tid;
        int o = idx / 640, k = idx - o * 640;
        float v;
        if (k < 128) v = root[(size_t)k * O + o];
        else { int r = (k - 128) >> 7, kk = (k - 128) & 127; v = W[((size_t)r * 128 + kk) * O + o]; }
        WT[idx] = __float2bfloat16(v);
    } else if (blk < PB_Q) {
        // q projection: K=768 split 4 ways (chain length 192), LDS reduce
        int g = blk - PB_W3;
        int o = tid & 63, kc = tid >> 6;
        const float* qr = qe + (size_t)g * QD;
        float s = 0.f;
        int k0 = kc * 192;
        for (int k = k0; k < k0 + 192; ++k)
            s = fmaf(qr[k], qn_W[(size_t)k * 64 + o], s);
        red[tid] = s;
        __syncthreads();
        if (tid < 64) {
            float t = red[tid] + red[tid + 64] + red[tid + 128] + red[tid + 192] + qn_b[o];
            q[g * 64 + o] = fmaxf(t, 0.f);
        }
    } else if (blk < PB_Z) {
        // zero the spare row (index NN) of both extended node buffers
        if (tid < 64) {
            ((unsigned*)((char*)xb0e + (size_t)NN * 256))[tid] = 0u;
            ((unsigned*)((char*)xb1e + (size_t)NN * 256))[tid] = 0u;
        }
    } else {
        // bucket histogram: 256 logical blocks, fixed stride 65536
        __shared__ int h[NBUCK];
        int hb = blk - PB_Z;
        for (int i = tid; i < NBUCK; i += 256) h[i] = 0;
        __syncthreads();
        for (int e = hb * 256 + tid; e < EE; e += 256 * 256)
            atomicAdd(&h[edst[e] >> 8], 1);
        __syncthreads();
        for (int i = tid; i < NBUCK; i += 256) if (h[i]) atomicAdd(&bcnt[i], h[i]);
    }
}

// ---------- CSR build: scan, bin, fine (proven kernels) ----------

__global__ void bucket_scan(const int* __restrict__ bcnt, int* __restrict__ bbase,
                            int* __restrict__ bcur) {
    __shared__ int wt[4];
    int tid = threadIdx.x, lane = tid & 63, w = tid >> 6;
    int v = (tid < NBUCK) ? bcnt[tid] : 0;
    int sc = v;
#pragma unroll
    for (int off = 1; off < 64; off <<= 1) {
        int t = __shfl_up(sc, off, 64);
        if (lane >= off) sc += t;
    }
    if (lane == 63) wt[w] = sc;
    __syncthreads();
    int wbase = 0;
    for (int ww = 0; ww < w; ++ww) wbase += wt[ww];
    int excl = wbase + sc - v;
    if (tid <= NBUCK) bbase[tid] = excl;   // tid==NBUCK gets total == EE
    if (tid < NBUCK) bcur[tid] = excl;
}

__global__ __launch_bounds__(256) void bin_edges(const int* __restrict__ src,
                                                 const int* __restrict__ dst,
                                                 const int* __restrict__ et,
                                                 int* __restrict__ bcur,
                                                 unsigned* __restrict__ binned) {
    __shared__ int lcnt[NBUCK];
    __shared__ int lbase[NBUCK];
    int tid = threadIdx.x;
    int e0 = blockIdx.x * EPB, e1 = min(e0 + EPB, EE);
    for (int base = e0; base < e1; base += 2048) {
        for (int i = tid; i < NBUCK; i += 256) lcnt[i] = 0;
        __syncthreads();
        unsigned ent[8]; int bk[8], rk[8];
#pragma unroll
        for (int k = 0; k < 8; ++k) {
            int e = base + k * 256 + tid;
            if (e < e1) {
                int d = dst[e];
                bk[k] = d >> 8;
                ent[k] = ((unsigned)src[e] << 10) | ((unsigned)et[e] << 8) | (unsigned)(d & 255);
                rk[k] = atomicAdd(&lcnt[bk[k]], 1);
            } else bk[k] = -1;
        }
        __syncthreads();
        for (int i = tid; i < NBUCK; i += 256)
            lbase[i] = lcnt[i] ? atomicAdd(&bcur[i], lcnt[i]) : 0;
        __syncthreads();
#pragma unroll
        for (int k = 0; k < 8; ++k)
            if (bk[k] >= 0) binned[lbase[bk[k]] + rk[k]] = ent[k];
        __syncthreads();
    }
}

__global__ __launch_bounds__(256) void csr_fine(const int* __restrict__ bbase,
                                                const unsigned* __restrict__ binned,
                                                int* __restrict__ csr,
                                                int* __restrict__ offsets,
                                                int4* __restrict__ cnt4) {
    __shared__ int cnt[1024];   // 256 nodes x 4 rels
    __shared__ int wt[4];
    int b = blockIdx.x, tid = threadIdx.x, lane = tid & 63, w = tid >> 6;
    int seg0 = bbase[b], seg1 = bbase[b + 1];
    for (int i = tid; i < 1024; i += 256) cnt[i] = 0;
    __syncthreads();
    for (int e = seg0 + tid; e < seg1; e += 256) {
        unsigned u = binned[e];
        atomicAdd(&cnt[(u & 255) * 4 + ((u >> 8) & 3)], 1);
    }
    __syncthreads();
    int c0 = cnt[tid * 4], c1 = cnt[tid * 4 + 1], c2 = cnt[tid * 4 + 2], c3 = cnt[tid * 4 + 3];
    int s = c0 + c1 + c2 + c3;
    int sc = s;
#pragma unroll
    for (int off = 1; off < 64; off <<= 1) {
        int t = __shfl_up(sc, off, 64);
        if (lane >= off) sc += t;
    }
    if (lane == 63) wt[w] = sc;
    __syncthreads();
    int wbase = 0;
    for (int ww = 0; ww < w; ++ww) wbase += wt[ww];
    int excl = wbase + sc - s;
    cnt[tid * 4]     = excl;
    cnt[tid * 4 + 1] = excl + c0;
    cnt[tid * 4 + 2] = excl + c0 + c1;
    cnt[tid * 4 + 3] = excl + c0 + c1 + c2;
    int node = b * 256 + tid;
    if (node < NN) {
        offsets[node] = seg0 + excl;
        cnt4[node] = make_int4(c0, c1, c2, c3);
    }
    if (b == NBUCK - 1 && tid == 0) offsets[NN] = EE;
    __syncthreads();
    for (int e = seg0 + tid; e < seg1; e += 256) {
        unsigned u = binned[e];
        int r = atomicAdd(&cnt[(u & 255) * 4 + ((u >> 8) & 3)], 1);
        csr[seg0 + r] = (int)(((u >> 10) << 2) | ((u >> 8) & 3));   // (src<<2)|rel
    }
}

// ---------- agg_x: 4-rel-wide dwordx4 gather, 2-slot unroll (round-7 proven) ----------
// Wave layout: lane = r*16 + l15. Group r (16 lanes) owns relation r; lane
// covers 16B (8 bf16 cols) of the source row. Per slot i: ONE csr dword load
// + ONE dwordx4 gather (OOB->0 masks i>=cs_r). 2 slots in flight — deeper
// unrolls (4-slot, pipelined meta) measurably regress (rounds 4, 10): more
// live state costs more than the added MLP buys.

__global__ __launch_bounds__(256) void agg_x(const __hip_bfloat16* __restrict__ X,
                                             const int* __restrict__ offsets,
                                             const int4* __restrict__ cnt4,
                                             const int* __restrict__ csr,
                                             __hip_bfloat16* __restrict__ X5agg) {
    int lane = threadIdx.x & 63;
    int gw = blockIdx.x * 4 + (threadIdx.x >> 6);
    int r = lane >> 4;
    int chunk = (lane & 15) * 16;

    v4i xsrd, csrd;
    xsrd.x = (int)(unsigned)(size_t)X;
    xsrd.y = (int)((size_t)X >> 32);      // stride=0
    xsrd.z = NN * 256;                    // num_records bytes -> OOB returns 0
    xsrd.w = 0x00020000;
    csrd.x = (int)(unsigned)(size_t)csr;
    csrd.y = (int)((size_t)csr >> 32);
    csrd.z = EE * 4;
    csrd.w = 0x00020000;

    for (int n0 = gw; n0 < NN; n0 += AGG_STRIDE) {
        int node = __builtin_amdgcn_readfirstlane(n0);
        int e0 = __builtin_amdgcn_readfirstlane(offsets[node]);
        int4 c4 = cnt4[node];
        int cs0 = __builtin_amdgcn_readfirstlane(c4.x);
        int cs1 = __builtin_amdgcn_readfirstlane(c4.y);
        int cs2 = __builtin_amdgcn_readfirstlane(c4.z);
        int cs3 = __builtin_amdgcn_readfirstlane(c4.w);
        int maxc = max(max(cs0, cs1), max(cs2, cs3));
        // per-lane segment start / count for this lane's relation
        int st_v = ((r >= 1) ? cs0 : 0) + ((r >= 2) ? cs1 : 0) + ((r >= 3) ? cs2 : 0);
        int cs_v = (r == 0) ? cs0 : ((r == 1) ? cs1 : ((r == 2) ? cs2 : cs3));
        int basev = (e0 + st_v) * 4;       // csr byte offset of slot 0

        float aF[8] = {0.f, 0.f, 0.f, 0.f, 0.f, 0.f, 0.f, 0.f};

        for (int i = 0; i < maxc; i += 2) {
            int pkA = __llvm_amdgcn_raw_buffer_load_i32(csrd, basev, i * 4, 0);
            int pkB = __llvm_amdgcn_raw_buffer_load_i32(csrd, basev, i * 4 + 4, 0);
            int vA = ((pkA >> 2) << 8) + chunk;          // src*256 + lane chunk
            int vB = ((pkB >> 2) << 8) + chunk;
            vA = (i < cs_v) ? vA : 0x7F000000;           // OOB -> HW returns 0
            vB = (i + 1 < cs_v) ? vB : 0x7F000000;
            v4i uA = __llvm_amdgcn_raw_buffer_load_v4i32(xsrd, vA, 0, 0);
            v4i uB = __llvm_amdgcn_raw_buffer_load_v4i32(xsrd, vB, 0, 0);
#pragma unroll
            for (int d = 0; d < 4; ++d) {
                aF[d * 2]     += bflo((unsigned)uA[d]);
                aF[d * 2 + 1] += bfhi((unsigned)uA[d]);
                aF[d * 2]     += bflo((unsigned)uB[d]);
                aF[d * 2 + 1] += bfhi((unsigned)uB[d]);
            }
        }

        float iv = 1.f / fmaxf((float)cs_v, 1.f);
        union { uint4 u; unsigned short h[8]; } o;
#pragma unroll
        for (int d = 0; d < 8; ++d) {
            __hip_bfloat16 g = __float2bfloat16(aF[d] * iv);
            o.h[d] = *(unsigned short*)&g;
        }
        *(uint4*)((char*)X5agg + (size_t)node * 1024 + lane * 16) = o.u;
    }
}

// ---------- dense5: out[N][O] = [Xself | X5agg] @ W5T^T + bias, fused epilogue ----------
// 64-row tiles (grid 782 = 3.05 blocks/CU -> balanced tail vs 391 = 1.53).
// Extra weight re-staging is L2-resident (160 KB unique) -> ~2 us/layer cost
// against a ~10-15 us tail win. One wave owns 16 rows.
// MODE 0: O=64, relu, write bf16 [h | q[batch]] (128 cols). MODE 1: O=128,
// relu bf16. MODE 2: O=64, no relu, fp32 to out.

template <int O, int MODE>
__global__ __launch_bounds__(256) void dense5(const __hip_bfloat16* __restrict__ Xself,
                                              const __hip_bfloat16* __restrict__ X5agg,
                                              const __hip_bfloat16* __restrict__ W5T,
                                              const float* __restrict__ bias,
                                              const float* __restrict__ q,
                                              const int* __restrict__ batch,
                                              __hip_bfloat16* __restrict__ xnext,
                                              float* __restrict__ out) {
    __shared__ char lds[16384];
    constexpr int NCT = O / 16;
    int tid = threadIdx.x;
    int wave = tid >> 6, lane = tid & 63;
    int quad = lane >> 4, l15 = lane & 15;
    int mbase = blockIdx.x * 64 + wave * 16;
    const __bf16* Ws = (const __bf16*)W5T;

    f32x4 acc[NCT];
#pragma unroll
    for (int t = 0; t < NCT; ++t) acc[t] = f32x4{0, 0, 0, 0};

    int arow0 = min(mbase + l15, NN - 1);
    const __bf16* aps0 = (const __bf16*)Xself + (size_t)arow0 * 128;
    const __bf16* apg0 = (const __bf16*)X5agg + (size_t)arow0 * 512;

    for (int kc = 0; kc < 10; ++kc) {
        int k0 = kc * 64;
        const __bf16* a0base = (kc < 2) ? aps0 + kc * 64 : apg0 + (kc - 2) * 64;
        __syncthreads();
        constexpr int NF = NCT * 2 * 64;     // fragments per chunk (512 / 1024)
#pragma unroll
        for (int i = 0; i < NF / 256; ++i) {
            int f = tid + i * 256;
            int fl = f & 63;
            int o = (f >> 7) * 16 + (fl & 15);
            int kk = k0 + ((f >> 6) & 1) * 32 + ((fl >> 4) & 3) * 8;
            *(uint4*)(lds + f * 16) = *(const uint4*)(Ws + (size_t)o * 640 + kk);
        }
        __syncthreads();
#pragma unroll
        for (int ks = 0; ks < 2; ++ks) {
            bf16x8 a0 = *(const bf16x8*)(a0base + ks * 32 + quad * 8);
#pragma unroll
            for (int t = 0; t < NCT; ++t) {
                bf16x8 b = *(const bf16x8*)(lds + ((t * 2 + ks) * 64 + lane) * 16);
                acc[t] = __builtin_amdgcn_mfma_f32_16x16x32_bf16(a0, b, acc[t], 0, 0, 0);
            }
        }
    }
    __syncthreads();

    if (MODE == 2) {
#pragma unroll
        for (int t = 0; t < NCT; ++t) {
            int col = t * 16 + l15;
            float bv = bias[col];
#pragma unroll
            for (int reg = 0; reg < 4; ++reg) {
                int row = mbase + quad * 4 + reg;
                if (row < NN) out[(size_t)row * 64 + col] = acc[t][reg] + bv;
            }
        }
        return;
    }

    // bf16 path: per-wave LDS tile [16][128]
    __hip_bfloat16* tp = (__hip_bfloat16*)(lds + wave * 4096);
    int m0 = mbase;
#pragma unroll
    for (int t = 0; t < NCT; ++t) {
        int col = t * 16 + l15;
        float bv = bias[col];
#pragma unroll
        for (int reg = 0; reg < 4; ++reg)
            tp[(quad * 4 + reg) * 128 + col] =
                __float2bfloat16(fmaxf(acc[t][reg] + bv, 0.f));
    }
    if (MODE == 0) {
        // fill q columns 64..127: lane -> row=lane>>2, colseg=(lane&3)*16
        int row = lane >> 2;
        int cs = (lane & 3) * 16;
        int rnode = min(m0 + row, NN - 1);
        int g = batch[rnode];
#pragma unroll
        for (int i = 0; i < 4; ++i) {
            float4 v = *(const float4*)(q + g * 64 + cs + i * 4);
            __hip_bfloat16 q0 = __float2bfloat16(v.x), q1 = __float2bfloat16(v.y);
            __hip_bfloat16 q2 = __float2bfloat16(v.z), q3 = __float2bfloat16(v.w);
            ushort4 pk;
            pk.x = *(unsigned short*)&q0; pk.y = *(unsigned short*)&q1;
            pk.z = *(unsigned short*)&q2; pk.w = *(unsigned short*)&q3;
            *(ushort4*)(tp + row * 128 + 64 + cs + i * 4) = pk;
        }
    }
    // store 16 rows x 256 B, 16B/lane coalesced
#pragma unroll
    for (int p = 0; p < 4; ++p) {
        int c = p * 64 + lane;
        int row = m0 + (c >> 4);
        if (row < NN)
            *(uint4*)((char*)xnext + (size_t)row * 256 + (c & 15) * 16) =
                *(const uint4*)((const char*)tp + c * 16);
    }
}

// ---------- launch ----------

static inline size_t rup(size_t x) { return (x + 255) & ~(size_t)255; }

extern "C" void kernel_launch(void* const* d_in, const int* in_sizes, int n_in,
                              void* d_out, int out_size, void* d_ws, size_t ws_size,
                              hipStream_t stream) {
    const float* x      = (const float*)d_in[0];
    const int*   esrc   = (const int*)d_in[1];
    const int*   edst   = esrc + EE;
    const int*   eattr  = (const int*)d_in[2];
    const int*   batch  = (const int*)d_in[3];
    const float* qe     = (const float*)d_in[4];
    const float* qn_W   = (const float*)d_in[5];
    const float* qn_b   = (const float*)d_in[6];
    const float* W0 = (const float*)d_in[7],  *root0 = (const float*)d_in[8],  *b0 = (const float*)d_in[9];
    const float* W1 = (const float*)d_in[10], *root1 = (const float*)d_in[11], *b1 = (const float*)d_in[12];
    const float* W2 = (const float*)d_in[13], *root2 = (const float*)d_in[14], *b2 = (const float*)d_in[15];
    const float* W3 = (const float*)d_in[16], *root3 = (const float*)d_in[17], *b3 = (const float*)d_in[18];
    float* out = (float*)d_out;

    char* w = (char*)d_ws;
    float* q       = (float*)w;  w += rup(GG * 64 * 4);
    int*   offsets = (int*)w;    w += rup(((size_t)NN + 1) * 4);
    int4*  cnt4    = (int4*)w;   w += rup((size_t)NN * 16);
    int*   bcnt    = (int*)w;    w += rup((size_t)NBUCK * 4);
    int*   bbase   = (int*)w;    w += rup(((size_t)NBUCK + 1) * 4);
    int*   bcur    = (int*)w;    w += rup((size_t)NBUCK * 4);
    unsigned* binned = (unsigned*)w; w += rup((size_t)EE * 4);
    int*   csr     = (int*)w;    w += rup((size_t)EE * 4);
    __hip_bfloat16* W5T0 = (__hip_bfloat16*)w; w += rup((size_t)64 * 640 * 2);
    __hip_bfloat16* W5T1 = (__hip_bfloat16*)w; w += rup((size_t)128 * 640 * 2);
    __hip_bfloat16* W5T2 = (__hip_bfloat16*)w; w += rup((size_t)128 * 640 * 2);
    __hip_bfloat16* W5T3 = (__hip_bfloat16*)w; w += rup((size_t)64 * 640 * 2);
    __hip_bfloat16* xb0 = (__hip_bfloat16*)w;  w += rup(((size_t)NN + 1) * 128 * 2);  // +1 spare row
    __hip_bfloat16* xb1 = (__hip_bfloat16*)w;  w += rup(((size_t)NN + 1) * 128 * 2);  // +1 spare row
    __hip_bfloat16* X5  = (__hip_bfloat16*)w;  w += rup((size_t)NN * 512 * 2);

    hipMemsetAsync(bcnt, 0, (size_t)NBUCK * 4, stream);

    // fused prep: conversion + weight transposes + q projection + zero-rows + histogram
    prep_hist<<<PB_HIST, 256, 0, stream>>>(x, xb0, xb1, qe, qn_W, qn_b, q,
                                           W0, root0, W5T0, W1, root1, W5T1,
                                           W2, root2, W5T2, W3, root3, W5T3,
                                           edst, bcnt);

    bucket_scan<<<1, 256, 0, stream>>>(bcnt, bbase, bcur);
    bin_edges<<<(EE + EPB - 1) / EPB, 256, 0, stream>>>(esrc, edst, eattr, bcur, binned);
    csr_fine<<<NBUCK, 256, 0, stream>>>(bbase, binned, csr, offsets, cnt4);

    int dblk = (NN + 63) / 64;             // 782

    // layer 0: xb0 -> X5 -> [h|q] xb1
    agg_x<<<AGG_GRID, 256, 0, stream>>>(xb0, offsets, cnt4, csr, X5);
    dense5<64, 0><<<dblk, 256, 0, stream>>>(xb0, X5, W5T0, b0, q, batch, xb1, nullptr);

    // layer 1: xb1 -> X5 -> xb0
    agg_x<<<AGG_GRID, 256, 0, stream>>>(xb1, offsets, cnt4, csr, X5);
    dense5<128, 1><<<dblk, 256, 0, stream>>>(xb1, X5, W5T1, b1, nullptr, nullptr, xb0, nullptr);

    // layer 2: xb0 -> X5 -> xb1
    agg_x<<<AGG_GRID, 256, 0, stream>>>(xb0, offsets, cnt4, csr, X5);
    dense5<128, 1><<<dblk, 256, 0, stream>>>(xb0, X5, W5T2, b2, nullptr, nullptr, xb1, nullptr);

    // layer 3: xb1 -> X5 -> fp32 out
    agg_x<<<AGG_GRID, 256, 0, stream>>>(xb1, offsets, cnt4, csr, X5);
    dense5<64, 2><<<dblk, 256, 0, stream>>>(xb1, X5, W5T3, b3, nullptr, nullptr, nullptr, out);
}

// Round 12
// 372.943 us; speedup vs baseline: 1.0638x; 1.0638x over previous
//
#include <hip/hip_runtime.h>
#include <hip/hip_bf16.h>

#define NN 50000
#define EE 800000
#define GG 16
#define QD 768
#define NBUCK 196      // ceil(50000/256) dst-buckets of 256 nodes
#define EPB 2048       // edges per block in bin_edges (391 blocks; one chunk each)

#define AGG_GRID 2048            // long-lived blocks: 8/CU
#define AGG_STRIDE (AGG_GRID * 4)

typedef __bf16 bf16x8 __attribute__((ext_vector_type(8)));
typedef float f32x4 __attribute__((ext_vector_type(4)));
typedef int v4i __attribute__((ext_vector_type(4)));

// raw buffer loads (HW bounds check: OOB returns 0 — validated rounds 6/7).
extern "C" __device__ int __llvm_amdgcn_raw_buffer_load_i32(v4i rsrc, int voffset,
                                                            int soffset, int aux)
    __asm("llvm.amdgcn.raw.buffer.load.i32");
extern "C" __device__ v4i __llvm_amdgcn_raw_buffer_load_v4i32(v4i rsrc, int voffset,
                                                              int soffset, int aux)
    __asm("llvm.amdgcn.raw.buffer.load.v4i32");

static __device__ __forceinline__ float bflo(unsigned u) {
    union { unsigned v; float f; } c; c.v = u << 16; return c.f;
}
static __device__ __forceinline__ float bfhi(unsigned u) {
    union { unsigned v; float f; } c; c.v = u & 0xffff0000u; return c.f;
}

// ---------- fused prep + bucket_hist, range-dispatched ----------
// W5T[o][k], k in [0,640): k<128 -> root[k][o]; else r=(k-128)>>7 -> W[r][(k-128)&127][o]

#define PB_CVT 6250                 // NN*128/4 / 256
#define PB_W0  (PB_CVT + 160)       // 64*640/256
#define PB_W1  (PB_W0 + 320)       // 128*640/256
#define PB_W2  (PB_W1 + 320)
#define PB_W3  (PB_W2 + 160)
#define PB_Q   (PB_W3 + 16)         // 16 graphs, one block each
#define PB_Z   (PB_Q + 1)           // zero extended rows NN of xb0/xb1
#define PB_HIST (PB_Z + 256)        // 256 histogram blocks (bcnt pre-zeroed by memset)

__global__ __launch_bounds__(256) void prep_hist(
        const float* __restrict__ x, __hip_bfloat16* __restrict__ xb0e,
        __hip_bfloat16* __restrict__ xb1e,
        const float* __restrict__ qe, const float* __restrict__ qn_W,
        const float* __restrict__ qn_b, float* __restrict__ q,
        const float* __restrict__ W0, const float* __restrict__ root0, __hip_bfloat16* __restrict__ W5T0,
        const float* __restrict__ W1, const float* __restrict__ root1, __hip_bfloat16* __restrict__ W5T1,
        const float* __restrict__ W2, const float* __restrict__ root2, __hip_bfloat16* __restrict__ W5T2,
        const float* __restrict__ W3, const float* __restrict__ root3, __hip_bfloat16* __restrict__ W5T3,
        const int* __restrict__ edst, int* __restrict__ bcnt) {
    __shared__ float red[256];
    int blk = blockIdx.x, tid = threadIdx.x;
    if (blk < PB_CVT) {
        int i = blk * 256 + tid;              // float4 index
        float4 v = ((const float4*)x)[i];
        union { ushort4 u; __hip_bfloat16 h[4]; } o;
        o.h[0] = __float2bfloat16(v.x); o.h[1] = __float2bfloat16(v.y);
        o.h[2] = __float2bfloat16(v.z); o.h[3] = __float2bfloat16(v.w);
        ((ushort4*)xb0e)[i] = o.u;
    } else if (blk < PB_W3) {
        const float* W; const float* root; __hip_bfloat16* WT; int O, base;
        if (blk < PB_W0)      { W = W0; root = root0; WT = W5T0; O = 64;  base = PB_CVT; }
        else if (blk < PB_W1) { W = W1; root = root1; WT = W5T1; O = 128; base = PB_W0; }
        else if (blk < PB_W2) { W = W2; root = root2; WT = W5T2; O = 128; base = PB_W1; }
        else                  { W = W3; root = root3; WT = W5T3; O = 64;  base = PB_W2; }
        int idx = (blk - base) * 256 + tid;
        int o = idx / 640, k = idx - o * 640;
        float v;
        if (k < 128) v = root[(size_t)k * O + o];
        else { int r = (k - 128) >> 7, kk = (k - 128) & 127; v = W[((size_t)r * 128 + kk) * O + o]; }
        WT[idx] = __float2bfloat16(v);
    } else if (blk < PB_Q) {
        // q projection: K=768 split 4 ways (chain length 192), LDS reduce
        int g = blk - PB_W3;
        int o = tid & 63, kc = tid >> 6;
        const float* qr = qe + (size_t)g * QD;
        float s = 0.f;
        int k0 = kc * 192;
        for (int k = k0; k < k0 + 192; ++k)
            s = fmaf(qr[k], qn_W[(size_t)k * 64 + o], s);
        red[tid] = s;
        __syncthreads();
        if (tid < 64) {
            float t = red[tid] + red[tid + 64] + red[tid + 128] + red[tid + 192] + qn_b[o];
            q[g * 64 + o] = fmaxf(t, 0.f);
        }
    } else if (blk < PB_Z) {
        // zero the spare row (index NN) of both extended node buffers
        if (tid < 64) {
            ((unsigned*)((char*)xb0e + (size_t)NN * 256))[tid] = 0u;
            ((unsigned*)((char*)xb1e + (size_t)NN * 256))[tid] = 0u;
        }
    } else {
        // bucket histogram: 256 logical blocks, fixed stride 65536
        __shared__ int h[NBUCK];
        int hb = blk - PB_Z;
        for (int i = tid; i < NBUCK; i += 256) h[i] = 0;
        __syncthreads();
        for (int e = hb * 256 + tid; e < EE; e += 256 * 256)
            atomicAdd(&h[edst[e] >> 8], 1);
        __syncthreads();
        for (int i = tid; i < NBUCK; i += 256) if (h[i]) atomicAdd(&bcnt[i], h[i]);
    }
}

// ---------- CSR build: scan, bin, fine (proven kernels) ----------

__global__ void bucket_scan(const int* __restrict__ bcnt, int* __restrict__ bbase,
                            int* __restrict__ bcur) {
    __shared__ int wt[4];
    int tid = threadIdx.x, lane = tid & 63, w = tid >> 6;
    int v = (tid < NBUCK) ? bcnt[tid] : 0;
    int sc = v;
#pragma unroll
    for (int off = 1; off < 64; off <<= 1) {
        int t = __shfl_up(sc, off, 64);
        if (lane >= off) sc += t;
    }
    if (lane == 63) wt[w] = sc;
    __syncthreads();
    int wbase = 0;
    for (int ww = 0; ww < w; ++ww) wbase += wt[ww];
    int excl = wbase + sc - v;
    if (tid <= NBUCK) bbase[tid] = excl;   // tid==NBUCK gets total == EE
    if (tid < NBUCK) bcur[tid] = excl;
}

__global__ __launch_bounds__(256) void bin_edges(const int* __restrict__ src,
                                                 const int* __restrict__ dst,
                                                 const int* __restrict__ et,
                                                 int* __restrict__ bcur,
                                                 unsigned* __restrict__ binned) {
    __shared__ int lcnt[NBUCK];
    __shared__ int lbase[NBUCK];
    int tid = threadIdx.x;
    int e0 = blockIdx.x * EPB, e1 = min(e0 + EPB, EE);
    for (int base = e0; base < e1; base += 2048) {
        for (int i = tid; i < NBUCK; i += 256) lcnt[i] = 0;
        __syncthreads();
        unsigned ent[8]; int bk[8], rk[8];
#pragma unroll
        for (int k = 0; k < 8; ++k) {
            int e = base + k * 256 + tid;
            if (e < e1) {
                int d = dst[e];
                bk[k] = d >> 8;
                ent[k] = ((unsigned)src[e] << 10) | ((unsigned)et[e] << 8) | (unsigned)(d & 255);
                rk[k] = atomicAdd(&lcnt[bk[k]], 1);
            } else bk[k] = -1;
        }
        __syncthreads();
        for (int i = tid; i < NBUCK; i += 256)
            lbase[i] = lcnt[i] ? atomicAdd(&bcur[i], lcnt[i]) : 0;
        __syncthreads();
#pragma unroll
        for (int k = 0; k < 8; ++k)
            if (bk[k] >= 0) binned[lbase[bk[k]] + rk[k]] = ent[k];
        __syncthreads();
    }
}

__global__ __launch_bounds__(256) void csr_fine(const int* __restrict__ bbase,
                                                const unsigned* __restrict__ binned,
                                                int* __restrict__ csr,
                                                int* __restrict__ offsets,
                                                int4* __restrict__ cnt4) {
    __shared__ int cnt[1024];   // 256 nodes x 4 rels
    __shared__ int wt[4];
    int b = blockIdx.x, tid = threadIdx.x, lane = tid & 63, w = tid >> 6;
    int seg0 = bbase[b], seg1 = bbase[b + 1];
    for (int i = tid; i < 1024; i += 256) cnt[i] = 0;
    __syncthreads();
    for (int e = seg0 + tid; e < seg1; e += 256) {
        unsigned u = binned[e];
        atomicAdd(&cnt[(u & 255) * 4 + ((u >> 8) & 3)], 1);
    }
    __syncthreads();
    int c0 = cnt[tid * 4], c1 = cnt[tid * 4 + 1], c2 = cnt[tid * 4 + 2], c3 = cnt[tid * 4 + 3];
    int s = c0 + c1 + c2 + c3;
    int sc = s;
#pragma unroll
    for (int off = 1; off < 64; off <<= 1) {
        int t = __shfl_up(sc, off, 64);
        if (lane >= off) sc += t;
    }
    if (lane == 63) wt[w] = sc;
    __syncthreads();
    int wbase = 0;
    for (int ww = 0; ww < w; ++ww) wbase += wt[ww];
    int excl = wbase + sc - s;
    cnt[tid * 4]     = excl;
    cnt[tid * 4 + 1] = excl + c0;
    cnt[tid * 4 + 2] = excl + c0 + c1;
    cnt[tid * 4 + 3] = excl + c0 + c1 + c2;
    int node = b * 256 + tid;
    if (node < NN) {
        offsets[node] = seg0 + excl;
        cnt4[node] = make_int4(c0, c1, c2, c3);
    }
    if (b == NBUCK - 1 && tid == 0) offsets[NN] = EE;
    __syncthreads();
    for (int e = seg0 + tid; e < seg1; e += 256) {
        unsigned u = binned[e];
        int r = atomicAdd(&cnt[(u & 255) * 4 + ((u >> 8) & 3)], 1);
        csr[seg0 + r] = (int)(((u >> 10) << 2) | ((u >> 8) & 3));   // (src<<2)|rel
    }
}

// ---------- agg_x: 4-rel-wide dwordx4 gather, 2-slot unroll (round-7 proven) ----------
// Wave layout: lane = r*16 + l15. Group r (16 lanes) owns relation r; lane
// covers 16B (8 bf16 cols) of the source row. Per slot i: ONE csr dword load
// + ONE dwordx4 gather (OOB->0 masks i>=cs_r). 2 slots in flight — deeper
// unrolls (4-slot, pipelined meta) measurably regress (rounds 4, 10).

__global__ __launch_bounds__(256) void agg_x(const __hip_bfloat16* __restrict__ X,
                                             const int* __restrict__ offsets,
                                             const int4* __restrict__ cnt4,
                                             const int* __restrict__ csr,
                                             __hip_bfloat16* __restrict__ X5agg) {
    int lane = threadIdx.x & 63;
    int gw = blockIdx.x * 4 + (threadIdx.x >> 6);
    int r = lane >> 4;
    int chunk = (lane & 15) * 16;

    v4i xsrd, csrd;
    xsrd.x = (int)(unsigned)(size_t)X;
    xsrd.y = (int)((size_t)X >> 32);      // stride=0
    xsrd.z = NN * 256;                    // num_records bytes -> OOB returns 0
    xsrd.w = 0x00020000;
    csrd.x = (int)(unsigned)(size_t)csr;
    csrd.y = (int)((size_t)csr >> 32);
    csrd.z = EE * 4;
    csrd.w = 0x00020000;

    for (int n0 = gw; n0 < NN; n0 += AGG_STRIDE) {
        int node = __builtin_amdgcn_readfirstlane(n0);
        int e0 = __builtin_amdgcn_readfirstlane(offsets[node]);
        int4 c4 = cnt4[node];
        int cs0 = __builtin_amdgcn_readfirstlane(c4.x);
        int cs1 = __builtin_amdgcn_readfirstlane(c4.y);
        int cs2 = __builtin_amdgcn_readfirstlane(c4.z);
        int cs3 = __builtin_amdgcn_readfirstlane(c4.w);
        int maxc = max(max(cs0, cs1), max(cs2, cs3));
        // per-lane segment start / count for this lane's relation
        int st_v = ((r >= 1) ? cs0 : 0) + ((r >= 2) ? cs1 : 0) + ((r >= 3) ? cs2 : 0);
        int cs_v = (r == 0) ? cs0 : ((r == 1) ? cs1 : ((r == 2) ? cs2 : cs3));
        int basev = (e0 + st_v) * 4;       // csr byte offset of slot 0

        float aF[8] = {0.f, 0.f, 0.f, 0.f, 0.f, 0.f, 0.f, 0.f};

        for (int i = 0; i < maxc; i += 2) {
            int pkA = __llvm_amdgcn_raw_buffer_load_i32(csrd, basev, i * 4, 0);
            int pkB = __llvm_amdgcn_raw_buffer_load_i32(csrd, basev, i * 4 + 4, 0);
            int vA = ((pkA >> 2) << 8) + chunk;          // src*256 + lane chunk
            int vB = ((pkB >> 2) << 8) + chunk;
            vA = (i < cs_v) ? vA : 0x7F000000;           // OOB -> HW returns 0
            vB = (i + 1 < cs_v) ? vB : 0x7F000000;
            v4i uA = __llvm_amdgcn_raw_buffer_load_v4i32(xsrd, vA, 0, 0);
            v4i uB = __llvm_amdgcn_raw_buffer_load_v4i32(xsrd, vB, 0, 0);
#pragma unroll
            for (int d = 0; d < 4; ++d) {
                aF[d * 2]     += bflo((unsigned)uA[d]);
                aF[d * 2 + 1] += bfhi((unsigned)uA[d]);
                aF[d * 2]     += bflo((unsigned)uB[d]);
                aF[d * 2 + 1] += bfhi((unsigned)uB[d]);
            }
        }

        float iv = 1.f / fmaxf((float)cs_v, 1.f);
        union { uint4 u; unsigned short h[8]; } o;
#pragma unroll
        for (int d = 0; d < 8; ++d) {
            __hip_bfloat16 g = __float2bfloat16(aF[d] * iv);
            o.h[d] = *(unsigned short*)&g;
        }
        *(uint4*)((char*)X5agg + (size_t)node * 1024 + lane * 16) = o.u;
    }
}

// ---------- dense5: out[N][O] = [Xself | X5agg] @ W5T^T + bias, fused epilogue ----------
// 128-row tiles, grid 391 (round-7 proven; 64-row split regresses ~+20 us —
// doubled weight staging/barriers per output row outweighs tail balance).
// MODE 0: O=64, relu, write bf16 [h | q[batch]] (128 cols). MODE 1: O=128,
// relu bf16. MODE 2: O=64, no relu, fp32 to out.

template <int O, int MODE>
__global__ __launch_bounds__(256) void dense5(const __hip_bfloat16* __restrict__ Xself,
                                              const __hip_bfloat16* __restrict__ X5agg,
                                              const __hip_bfloat16* __restrict__ W5T,
                                              const float* __restrict__ bias,
                                              const float* __restrict__ q,
                                              const int* __restrict__ batch,
                                              __hip_bfloat16* __restrict__ xnext,
                                              float* __restrict__ out) {
    __shared__ char lds[16384];
    constexpr int NCT = O / 16;
    int tid = threadIdx.x;
    int wave = tid >> 6, lane = tid & 63;
    int quad = lane >> 4, l15 = lane & 15;
    int mbase = blockIdx.x * 128 + wave * 32;
    const __bf16* Ws = (const __bf16*)W5T;

    f32x4 acc[2][NCT];
#pragma unroll
    for (int mt = 0; mt < 2; ++mt)
#pragma unroll
        for (int t = 0; t < NCT; ++t) acc[mt][t] = f32x4{0, 0, 0, 0};

    int arow0 = min(mbase + l15, NN - 1);
    int arow1 = min(mbase + 16 + l15, NN - 1);
    const __bf16* aps0 = (const __bf16*)Xself + (size_t)arow0 * 128;
    const __bf16* aps1 = (const __bf16*)Xself + (size_t)arow1 * 128;
    const __bf16* apg0 = (const __bf16*)X5agg + (size_t)arow0 * 512;
    const __bf16* apg1 = (const __bf16*)X5agg + (size_t)arow1 * 512;

    for (int kc = 0; kc < 10; ++kc) {
        int k0 = kc * 64;
        const __bf16* a0base = (kc < 2) ? aps0 + kc * 64 : apg0 + (kc - 2) * 64;
        const __bf16* a1base = (kc < 2) ? aps1 + kc * 64 : apg1 + (kc - 2) * 64;
        __syncthreads();
        constexpr int NF = NCT * 2 * 64;     // fragments per chunk (512 / 1024)
#pragma unroll
        for (int i = 0; i < NF / 256; ++i) {
            int f = tid + i * 256;
            int fl = f & 63;
            int o = (f >> 7) * 16 + (fl & 15);
            int kk = k0 + ((f >> 6) & 1) * 32 + ((fl >> 4) & 3) * 8;
            *(uint4*)(lds + f * 16) = *(const uint4*)(Ws + (size_t)o * 640 + kk);
        }
        __syncthreads();
#pragma unroll
        for (int ks = 0; ks < 2; ++ks) {
            bf16x8 a0 = *(const bf16x8*)(a0base + ks * 32 + quad * 8);
            bf16x8 a1 = *(const bf16x8*)(a1base + ks * 32 + quad * 8);
#pragma unroll
            for (int t = 0; t < NCT; ++t) {
                bf16x8 b = *(const bf16x8*)(lds + ((t * 2 + ks) * 64 + lane) * 16);
                acc[0][t] = __builtin_amdgcn_mfma_f32_16x16x32_bf16(a0, b, acc[0][t], 0, 0, 0);
                acc[1][t] = __builtin_amdgcn_mfma_f32_16x16x32_bf16(a1, b, acc[1][t], 0, 0, 0);
            }
        }
    }
    __syncthreads();

    if (MODE == 2) {
#pragma unroll
        for (int mt = 0; mt < 2; ++mt)
#pragma unroll
            for (int t = 0; t < NCT; ++t) {
                int col = t * 16 + l15;
                float bv = bias[col];
#pragma unroll
                for (int reg = 0; reg < 4; ++reg) {
                    int row = mbase + mt * 16 + quad * 4 + reg;
                    if (row < NN) out[(size_t)row * 64 + col] = acc[mt][t][reg] + bv;
                }
            }
        return;
    }

    // bf16 path: per-wave LDS tile [16][128], one row-tile at a time
    __hip_bfloat16* tp = (__hip_bfloat16*)(lds + wave * 4096);
#pragma unroll
    for (int mt = 0; mt < 2; ++mt) {
        int m0 = mbase + mt * 16;
#pragma unroll
        for (int t = 0; t < NCT; ++t) {
            int col = t * 16 + l15;
            float bv = bias[col];
#pragma unroll
            for (int reg = 0; reg < 4; ++reg)
                tp[(quad * 4 + reg) * 128 + col] =
                    __float2bfloat16(fmaxf(acc[mt][t][reg] + bv, 0.f));
        }
        if (MODE == 0) {
            // fill q columns 64..127: lane -> row=lane>>2, colseg=(lane&3)*16
            int row = lane >> 2;
            int cs = (lane & 3) * 16;
            int rnode = min(m0 + row, NN - 1);
            int g = batch[rnode];
#pragma unroll
            for (int i = 0; i < 4; ++i) {
                float4 v = *(const float4*)(q + g * 64 + cs + i * 4);
                __hip_bfloat16 q0 = __float2bfloat16(v.x), q1 = __float2bfloat16(v.y);
                __hip_bfloat16 q2 = __float2bfloat16(v.z), q3 = __float2bfloat16(v.w);
                ushort4 pk;
                pk.x = *(unsigned short*)&q0; pk.y = *(unsigned short*)&q1;
                pk.z = *(unsigned short*)&q2; pk.w = *(unsigned short*)&q3;
                *(ushort4*)(tp + row * 128 + 64 + cs + i * 4) = pk;
            }
        }
        // store 16 rows x 256 B, 16B/lane coalesced
#pragma unroll
        for (int p = 0; p < 4; ++p) {
            int c = p * 64 + lane;
            int row = m0 + (c >> 4);
            if (row < NN)
                *(uint4*)((char*)xnext + (size_t)row * 256 + (c & 15) * 16) =
                    *(const uint4*)((const char*)tp + c * 16);
        }
    }
}

// ---------- launch ----------

static inline size_t rup(size_t x) { return (x + 255) & ~(size_t)255; }

extern "C" void kernel_launch(void* const* d_in, const int* in_sizes, int n_in,
                              void* d_out, int out_size, void* d_ws, size_t ws_size,
                              hipStream_t stream) {
    const float* x      = (const float*)d_in[0];
    const int*   esrc   = (const int*)d_in[1];
    const int*   edst   = esrc + EE;
    const int*   eattr  = (const int*)d_in[2];
    const int*   batch  = (const int*)d_in[3];
    const float* qe     = (const float*)d_in[4];
    const float* qn_W   = (const float*)d_in[5];
    const float* qn_b   = (const float*)d_in[6];
    const float* W0 = (const float*)d_in[7],  *root0 = (const float*)d_in[8],  *b0 = (const float*)d_in[9];
    const float* W1 = (const float*)d_in[10], *root1 = (const float*)d_in[11], *b1 = (const float*)d_in[12];
    const float* W2 = (const float*)d_in[13], *root2 = (const float*)d_in[14], *b2 = (const float*)d_in[15];
    const float* W3 = (const float*)d_in[16], *root3 = (const float*)d_in[17], *b3 = (const float*)d_in[18];
    float* out = (float*)d_out;

    char* w = (char*)d_ws;
    float* q       = (float*)w;  w += rup(GG * 64 * 4);
    int*   offsets = (int*)w;    w += rup(((size_t)NN + 1) * 4);
    int4*  cnt4    = (int4*)w;   w += rup((size_t)NN * 16);
    int*   bcnt    = (int*)w;    w += rup((size_t)NBUCK * 4);
    int*   bbase   = (int*)w;    w += rup(((size_t)NBUCK + 1) * 4);
    int*   bcur    = (int*)w;    w += rup((size_t)NBUCK * 4);
    unsigned* binned = (unsigned*)w; w += rup((size_t)EE * 4);
    int*   csr     = (int*)w;    w += rup((size_t)EE * 4);
    __hip_bfloat16* W5T0 = (__hip_bfloat16*)w; w += rup((size_t)64 * 640 * 2);
    __hip_bfloat16* W5T1 = (__hip_bfloat16*)w; w += rup((size_t)128 * 640 * 2);
    __hip_bfloat16* W5T2 = (__hip_bfloat16*)w; w += rup((size_t)128 * 640 * 2);
    __hip_bfloat16* W5T3 = (__hip_bfloat16*)w; w += rup((size_t)64 * 640 * 2);
    __hip_bfloat16* xb0 = (__hip_bfloat16*)w;  w += rup(((size_t)NN + 1) * 128 * 2);  // +1 spare row
    __hip_bfloat16* xb1 = (__hip_bfloat16*)w;  w += rup(((size_t)NN + 1) * 128 * 2);  // +1 spare row
    __hip_bfloat16* X5  = (__hip_bfloat16*)w;  w += rup((size_t)NN * 512 * 2);

    hipMemsetAsync(bcnt, 0, (size_t)NBUCK * 4, stream);

    // fused prep: conversion + weight transposes + q projection + zero-rows + histogram
    prep_hist<<<PB_HIST, 256, 0, stream>>>(x, xb0, xb1, qe, qn_W, qn_b, q,
                                           W0, root0, W5T0, W1, root1, W5T1,
                                           W2, root2, W5T2, W3, root3, W5T3,
                                           edst, bcnt);

    bucket_scan<<<1, 256, 0, stream>>>(bcnt, bbase, bcur);
    bin_edges<<<(EE + EPB - 1) / EPB, 256, 0, stream>>>(esrc, edst, eattr, bcur, binned);
    csr_fine<<<NBUCK, 256, 0, stream>>>(bbase, binned, csr, offsets, cnt4);

    int dblk = (NN + 127) / 128;           // 391

    // layer 0: xb0 -> X5 -> [h|q] xb1
    agg_x<<<AGG_GRID, 256, 0, stream>>>(xb0, offsets, cnt4, csr, X5);
    dense5<64, 0><<<dblk, 256, 0, stream>>>(xb0, X5, W5T0, b0, q, batch, xb1, nullptr);

    // layer 1: xb1 -> X5 -> xb0
    agg_x<<<AGG_GRID, 256, 0, stream>>>(xb1, offsets, cnt4, csr, X5);
    dense5<128, 1><<<dblk, 256, 0, stream>>>(xb1, X5, W5T1, b1, nullptr, nullptr, xb0, nullptr);

    // layer 2: xb0 -> X5 -> xb1
    agg_x<<<AGG_GRID, 256, 0, stream>>>(xb0, offsets, cnt4, csr, X5);
    dense5<128, 1><<<dblk, 256, 0, stream>>>(xb0, X5, W5T2, b2, nullptr, nullptr, xb1, nullptr);

    // layer 3: xb1 -> X5 -> fp32 out
    agg_x<<<AGG_GRID, 256, 0, stream>>>(xb1, offsets, cnt4, csr, X5);
    dense5<64, 2><<<dblk, 256, 0, stream>>>(xb1, X5, W5T3, b3, nullptr, nullptr, nullptr, out);
}